// Round 2
// baseline (1563.841 us; speedup 1.0000x reference)
//
#include <hip/hip_runtime.h>
#include <hip/hip_bf16.h>

namespace {

constexpr int B  = 2;
constexpr int S  = 2048;
constexpr int D  = 1024;
constexpr int H  = 16;
constexpr int HD = 64;
constexpr float SCALE = 0.125f;   // HD^-0.5

// ---------------- fp32 tiled GEMM: C[M,N] = A[M,K] @ W[N,K]^T + bias[N] ----
constexpr int GBM = 64, GBN = 64, GBK = 16;

__global__ __launch_bounds__(256) void gemm_bias_k(
    const float* __restrict__ A, const float* __restrict__ W,
    const float* __restrict__ bias, float* __restrict__ C,
    int M, int N, int K)
{
  __shared__ __align__(16) float As[GBK][GBM + 4];   // [k][m], row stride 68*4=272B (16B mult)
  __shared__ __align__(16) float Ws[GBK][GBN + 4];   // [k][n]

  const int tid = threadIdx.x;
  const int bm  = blockIdx.y * GBM;
  const int bn  = blockIdx.x * GBN;
  const int tx  = tid & 15;        // 16 cols of threads
  const int ty  = tid >> 4;        // 16 rows of threads
  const int lr  = tid >> 2;        // load row 0..63
  const int lc  = (tid & 3) << 2;  // load col {0,4,8,12}

  float acc[4][4] = {};

  for (int k0 = 0; k0 < K; k0 += GBK) {
    float4 av = *(const float4*)&A[(size_t)(bm + lr) * K + k0 + lc];
    float4 wv = *(const float4*)&W[(size_t)(bn + lr) * K + k0 + lc];
    As[lc + 0][lr] = av.x; As[lc + 1][lr] = av.y;
    As[lc + 2][lr] = av.z; As[lc + 3][lr] = av.w;
    Ws[lc + 0][lr] = wv.x; Ws[lc + 1][lr] = wv.y;
    Ws[lc + 2][lr] = wv.z; Ws[lc + 3][lr] = wv.w;
    __syncthreads();
#pragma unroll
    for (int k = 0; k < GBK; ++k) {
      float4 a4 = *(const float4*)&As[k][ty * 4];
      float4 w4 = *(const float4*)&Ws[k][tx * 4];
      float a[4] = {a4.x, a4.y, a4.z, a4.w};
      float w[4] = {w4.x, w4.y, w4.z, w4.w};
#pragma unroll
      for (int i = 0; i < 4; ++i)
#pragma unroll
        for (int j = 0; j < 4; ++j)
          acc[i][j] += a[i] * w[j];
    }
    __syncthreads();
  }

  float4 bv = *(const float4*)&bias[bn + tx * 4];
  float bb[4] = {bv.x, bv.y, bv.z, bv.w};
#pragma unroll
  for (int i = 0; i < 4; ++i) {
    float4 cv;
    cv.x = acc[i][0] + bb[0];
    cv.y = acc[i][1] + bb[1];
    cv.z = acc[i][2] + bb[2];
    cv.w = acc[i][3] + bb[3];
    *(float4*)&C[(size_t)(bm + ty * 4 + i) * N + bn + tx * 4] = cv;
  }
}

// ---------------- flash attention with structural bias ---------------------
// grid: (S/32, B*H); block: 256 threads.
// Each block: one (b,h), 32 query rows. Iterates 32-key tiles with online
// softmax. Octx may alias Q (block reads exactly the region it later writes).
constexpr int QT = 32, KT = 32;

__global__ __launch_bounds__(256) void attn_flash_k(
    const float* __restrict__ Q, const float* __restrict__ Kp,
    const float* __restrict__ Vp, const float* __restrict__ biasS,
    const float* __restrict__ lambda_p, float* __restrict__ Octx)
{
  __shared__ __align__(16) float Qs[QT][HD + 4];
  __shared__ __align__(16) float Ks[KT][HD + 4];
  __shared__ __align__(16) float Vs[KT][HD + 4];
  __shared__ float Ps[QT][KT + 4];

  const int tid = threadIdx.x;
  const int b   = blockIdx.y >> 4;   // H = 16
  const int h   = blockIdx.y & 15;
  const int q0  = blockIdx.x * QT;
  const float lam = lambda_p[0];
  const size_t hoff = (size_t)h * HD;

  // load Q tile: 32x64 floats = 512 float4, 2 per thread
#pragma unroll
  for (int it = 0; it < 2; ++it) {
    int idx = tid + it * 256;
    int r  = idx >> 4;
    int c  = (idx & 15) << 2;
    *(float4*)&Qs[r][c] =
        *(const float4*)&Q[(size_t)(b * S + q0 + r) * D + hoff + c];
  }

  const int r  = tid >> 3;        // row 0..31 (consistent across phases)
  const int cg = tid & 7;         // 8 lanes per row
  const int oc = cg * 8;          // output cols [oc, oc+8)

  float m_r = -1e30f, l_r = 0.0f;
  float o[8] = {};

  for (int k0 = 0; k0 < S; k0 += KT) {
    __syncthreads();   // prev PV done with Ks/Vs/Ps
    // load K,V tiles
#pragma unroll
    for (int it = 0; it < 2; ++it) {
      int idx = tid + it * 256;
      int rr = idx >> 4;
      int cc = (idx & 15) << 2;
      *(float4*)&Ks[rr][cc] =
          *(const float4*)&Kp[(size_t)(b * S + k0 + rr) * D + hoff + cc];
      *(float4*)&Vs[rr][cc] =
          *(const float4*)&Vp[(size_t)(b * S + k0 + rr) * D + hoff + cc];
    }
    __syncthreads();

    // scores: thread computes cols cg*4 .. cg*4+3 of row r
    float s[4] = {};
#pragma unroll
    for (int d4 = 0; d4 < HD / 4; ++d4) {
      float4 q4 = *(const float4*)&Qs[r][d4 * 4];
#pragma unroll
      for (int j = 0; j < 4; ++j) {
        float4 k4 = *(const float4*)&Ks[cg * 4 + j][d4 * 4];
        s[j] += q4.x * k4.x + q4.y * k4.y + q4.z * k4.z + q4.w * k4.w;
      }
    }
    float4 bv = *(const float4*)&biasS[((size_t)b * S + q0 + r) * S + k0 + cg * 4];
    s[0] = s[0] * SCALE + lam * bv.x;
    s[1] = s[1] * SCALE + lam * bv.y;
    s[2] = s[2] * SCALE + lam * bv.z;
    s[3] = s[3] * SCALE + lam * bv.w;

    // online softmax (8-lane group reduce; lanes of a row are consecutive)
    float tm = fmaxf(fmaxf(s[0], s[1]), fmaxf(s[2], s[3]));
#pragma unroll
    for (int w = 1; w < 8; w <<= 1) tm = fmaxf(tm, __shfl_xor(tm, w, 64));
    float nm = fmaxf(m_r, tm);
    float cf = __expf(m_r - nm);
    float psum = 0.0f;
#pragma unroll
    for (int j = 0; j < 4; ++j) {
      float p = __expf(s[j] - nm);
      Ps[r][cg * 4 + j] = p;
      psum += p;
    }
#pragma unroll
    for (int w = 1; w < 8; w <<= 1) psum += __shfl_xor(psum, w, 64);
    l_r = l_r * cf + psum;
    m_r = nm;
    __syncthreads();   // Ps complete before PV

    // PV: o[0..7] for cols oc..oc+7
#pragma unroll
    for (int i = 0; i < 8; ++i) o[i] *= cf;
#pragma unroll 8
    for (int kk = 0; kk < KT; ++kk) {
      float p = Ps[r][kk];
      float4 v0 = *(const float4*)&Vs[kk][oc];
      float4 v1 = *(const float4*)&Vs[kk][oc + 4];
      o[0] += p * v0.x; o[1] += p * v0.y; o[2] += p * v0.z; o[3] += p * v0.w;
      o[4] += p * v1.x; o[5] += p * v1.y; o[6] += p * v1.z; o[7] += p * v1.w;
    }
  }

  const float inv = 1.0f / l_r;
  float4 o0 = {o[0] * inv, o[1] * inv, o[2] * inv, o[3] * inv};
  float4 o1 = {o[4] * inv, o[5] * inv, o[6] * inv, o[7] * inv};
  float* dst = &Octx[(size_t)(b * S + q0 + r) * D + hoff + oc];
  *(float4*)&dst[0] = o0;
  *(float4*)&dst[4] = o1;
}

}  // namespace

extern "C" void kernel_launch(void* const* d_in, const int* in_sizes, int n_in,
                              void* d_out, int out_size, void* d_ws, size_t ws_size,
                              hipStream_t stream)
{
  const float* query = (const float*)d_in[0];
  const float* key   = (const float*)d_in[1];
  const float* value = (const float*)d_in[2];
  const float* biasS = (const float*)d_in[3];
  const float* Wq = (const float*)d_in[4];
  const float* bq = (const float*)d_in[5];
  const float* Wk = (const float*)d_in[6];
  const float* bk = (const float*)d_in[7];
  const float* Wv = (const float*)d_in[8];
  const float* bv = (const float*)d_in[9];
  const float* Wo = (const float*)d_in[10];
  const float* bo = (const float*)d_in[11];
  const float* lam = (const float*)d_in[12];
  float* out = (float*)d_out;

  const size_t planesz = (size_t)B * S * D;   // 4M floats = 16MB
  float* Qb = (float*)d_ws;
  float* Kb = Qb + planesz;
  float* Vb = Kb + planesz;
  // context aliases Qb (safe: each attn block reads only its own region of Q
  // before writing it back at the end)

  const int M = B * S;                 // 4096
  dim3 ggrid(D / GBN, M / GBM);        // (16, 64)

  gemm_bias_k<<<ggrid, 256, 0, stream>>>(query, Wq, bq, Qb, M, D, D);
  gemm_bias_k<<<ggrid, 256, 0, stream>>>(key,   Wk, bk, Kb, M, D, D);
  gemm_bias_k<<<ggrid, 256, 0, stream>>>(value, Wv, bv, Vb, M, D, D);

  dim3 agrid(S / QT, B * H);           // (64, 32)
  attn_flash_k<<<agrid, 256, 0, stream>>>(Qb, Kb, Vb, biasS, lam, Qb);

  gemm_bias_k<<<ggrid, 256, 0, stream>>>(Qb, Wo, bo, out, M, D, D);
}

// Round 3
// 612.045 us; speedup vs baseline: 2.5551x; 2.5551x over previous
//
#include <hip/hip_runtime.h>
#include <hip/hip_bf16.h>

namespace {

constexpr int B  = 2;
constexpr int S  = 2048;
constexpr int D  = 1024;
constexpr int H  = 16;
constexpr float SCALE = 0.125f;   // HD^-0.5

typedef __bf16 bf16x8 __attribute__((ext_vector_type(8)));
typedef float  f32x4  __attribute__((ext_vector_type(4)));
typedef unsigned short u16;
typedef u16 u16x8 __attribute__((ext_vector_type(8)));
typedef u16 u16x4 __attribute__((ext_vector_type(4)));

__device__ __forceinline__ u16 f2bf(float f) {
  union { float f; unsigned u; } v{f};
  unsigned r = v.u + 0x7fffu + ((v.u >> 16) & 1u);   // RNE
  return (u16)(r >> 16);
}

// ---------------- fp32 -> bf16 conversion (batched over blockIdx.z) --------
__global__ __launch_bounds__(256) void cvt3_k(
    const float* __restrict__ a, const float* __restrict__ b,
    const float* __restrict__ c, u16* __restrict__ da,
    u16* __restrict__ db, u16* __restrict__ dc)
{
  const float* s = (blockIdx.z == 0) ? a : (blockIdx.z == 1) ? b : c;
  u16* d = (blockIdx.z == 0) ? da : (blockIdx.z == 1) ? db : dc;
  size_t i = ((size_t)blockIdx.x * 256 + threadIdx.x) * 4;
  float4 v = *(const float4*)&s[i];
  u16x4 o = { f2bf(v.x), f2bf(v.y), f2bf(v.z), f2bf(v.w) };
  *(u16x4*)&d[i] = o;
}

__global__ __launch_bounds__(256) void cvt4_k(
    const float* __restrict__ a, const float* __restrict__ b,
    const float* __restrict__ c, const float* __restrict__ e,
    u16* __restrict__ da, u16* __restrict__ db,
    u16* __restrict__ dc, u16* __restrict__ de)
{
  const float* s = (blockIdx.z == 0) ? a : (blockIdx.z == 1) ? b
                 : (blockIdx.z == 2) ? c : e;
  u16* d = (blockIdx.z == 0) ? da : (blockIdx.z == 1) ? db
         : (blockIdx.z == 2) ? dc : de;
  size_t i = ((size_t)blockIdx.x * 256 + threadIdx.x) * 4;
  float4 v = *(const float4*)&s[i];
  u16x4 o = { f2bf(v.x), f2bf(v.y), f2bf(v.z), f2bf(v.w) };
  *(u16x4*)&d[i] = o;
}

// ---------------- bf16 MFMA GEMM: C[M,N] = A[M,K] @ W[N,K]^T + bias --------
// M=4096, N=1024, K=1024. Tile 64x128, BK=32, 4 waves (2x2), each wave 32x64.
// LDS kg-major: Xl[kg][row][8] so frag ds_read_b128 is 256B-contiguous per
// 16-lane group (conflict-free).
constexpr int GM = B * S;   // 4096
constexpr int GN = D;       // 1024
constexpr int GK = D;       // 1024

template <bool OUTBF>
__global__ __launch_bounds__(256) void gemm_bf16_k(
    const u16* __restrict__ A, const u16* __restrict__ W,
    const float* __restrict__ bias, u16* __restrict__ Cb,
    float* __restrict__ Cf)
{
  __shared__ u16 Al[4 * 64 * 8];     // [kg][row 0..63][8]
  __shared__ u16 Wl[4 * 128 * 8];    // [kg][row 0..127][8]

  const int tid  = threadIdx.x;
  const int lane = tid & 63;
  const int w    = tid >> 6;
  const int wr = w >> 1, wc = w & 1;
  const int lg = lane >> 4, ll = lane & 15;
  const int bm = blockIdx.y * 64, bn = blockIdx.x * 128;

  // staging: A = 256 chunks (1/thread), W = 512 chunks (2/thread)
  const int arow = tid & 63, akg = tid >> 6;           // 0..3
  const int wrow = tid & 127, wkg = tid >> 7;          // 0..1 (+2 for chunk 1)
  const u16* Ap = &A[(size_t)(bm + arow) * GK + akg * 8];
  const u16* Wp = &W[(size_t)(bn + wrow) * GK + wkg * 8];
  const int aoff  = akg * 512 + arow * 8;              // ushort units
  const int woff0 = wkg * 1024 + wrow * 8;
  const int woff1 = woff0 + 2048;

  f32x4 acc[2][4] = {};

  uint4 pa  = *(const uint4*)Ap;
  uint4 pw0 = *(const uint4*)Wp;
  uint4 pw1 = *(const uint4*)(Wp + 16);

  for (int k0 = 0; k0 < GK; k0 += 32) {
    __syncthreads();
    *(uint4*)&Al[aoff]  = pa;
    *(uint4*)&Wl[woff0] = pw0;
    *(uint4*)&Wl[woff1] = pw1;
    __syncthreads();
    if (k0 + 32 < GK) {
      pa  = *(const uint4*)(Ap + k0 + 32);
      pw0 = *(const uint4*)(Wp + k0 + 32);
      pw1 = *(const uint4*)(Wp + k0 + 48);
    }
    bf16x8 af[2], wf[4];
#pragma unroll
    for (int mi = 0; mi < 2; ++mi)
      af[mi] = *(const bf16x8*)&Al[lg * 512 + (wr * 32 + mi * 16 + ll) * 8];
#pragma unroll
    for (int ni = 0; ni < 4; ++ni)
      wf[ni] = *(const bf16x8*)&Wl[lg * 1024 + (wc * 64 + ni * 16 + ll) * 8];
#pragma unroll
    for (int mi = 0; mi < 2; ++mi)
#pragma unroll
      for (int ni = 0; ni < 4; ++ni)
        acc[mi][ni] = __builtin_amdgcn_mfma_f32_16x16x32_bf16(
            af[mi], wf[ni], acc[mi][ni], 0, 0, 0);
  }

#pragma unroll
  for (int ni = 0; ni < 4; ++ni) {
    const int gcol = bn + wc * 64 + ni * 16 + ll;
    const float bv = bias[gcol];
#pragma unroll
    for (int mi = 0; mi < 2; ++mi) {
      const int grow = bm + wr * 32 + mi * 16 + lg * 4;
#pragma unroll
      for (int r = 0; r < 4; ++r) {
        float v = acc[mi][ni][r] + bv;
        if (OUTBF) Cb[(size_t)(grow + r) * GN + gcol] = f2bf(v);
        else       Cf[(size_t)(grow + r) * GN + gcol] = v;
      }
    }
  }
}

// ---------------- V transpose: Vbf[b,s,h*64+d] -> Vt[(b*H+h)*64+d][s] ------
__global__ __launch_bounds__(256) void transpose_v_k(
    const u16* __restrict__ Vb, u16* __restrict__ Vt)
{
  __shared__ u16 T[64][72];
  const int tid = threadIdx.x;
  const int bh = blockIdx.y, b = bh >> 4, h = bh & 15;
  const int s0 = blockIdx.x * 64;
#pragma unroll
  for (int it = 0; it < 2; ++it) {
    int idx = tid + it * 256;
    int s = idx >> 3, dc = idx & 7;
    *(uint4*)&T[s][dc * 8] =
        *(const uint4*)&Vb[(size_t)(b * S + s0 + s) * D + h * 64 + dc * 8];
  }
  __syncthreads();
#pragma unroll
  for (int it = 0; it < 2; ++it) {
    int idx = tid + it * 256;
    int d = idx >> 3, sc = idx & 7;
    u16x8 o;
#pragma unroll
    for (int jj = 0; jj < 8; ++jj) o[jj] = T[sc * 8 + jj][d];
    *(u16x8*)&Vt[((size_t)bh * 64 + d) * S + s0 + sc * 8] = o;
  }
}

// ---------------- MFMA flash attention with structural bias ----------------
// grid (S/64, B*H), 256 threads = 4 waves; wave w owns 16 q-rows.
// K,V fragments read directly from global (L1/L2-cached). P via per-wave LDS.
__global__ __launch_bounds__(256) void attn_mfma_k(
    const u16* __restrict__ Qb, const u16* __restrict__ Kb,
    const u16* __restrict__ Vt, const float* __restrict__ biasS,
    const float* __restrict__ lamp, u16* __restrict__ Ob)
{
  __shared__ float Pl[4][16][68];
  const int tid  = threadIdx.x;
  const int lane = tid & 63;
  const int w    = tid >> 6;
  const int lg = lane >> 4, ll = lane & 15;
  const int bh = blockIdx.y, b = bh >> 4, h = bh & 15;
  const int qw = blockIdx.x * 64 + w * 16;   // wave's q base
  const float lam = lamp[0];

  // Q fragments (row = ll, k-slots d = lg*8+j within each 32-d step)
  bf16x8 aQ[2];
  {
    const u16* qrow = &Qb[(size_t)(b * S + qw + ll) * D + h * 64];
    aQ[0] = *(const bf16x8*)&qrow[lg * 8];
    aQ[1] = *(const bf16x8*)&qrow[32 + lg * 8];
  }

  const u16* Kbase = &Kb[(size_t)(b * S) * D + h * 64];
  const u16* Vbase = &Vt[(size_t)bh * 64 * S];
  const float* Bbase = &biasS[((size_t)b * S + qw) * S];

  f32x4 accO[4] = {};
  float m_r[4], l_r[4];
#pragma unroll
  for (int r = 0; r < 4; ++r) { m_r[r] = -1e30f; l_r[r] = 0.f; }

  for (int k0 = 0; k0 < S; k0 += 64) {
    // ---- QK^T: s[kf] covers kv cols kf*16+ll, q rows lg*4+r ----
    f32x4 sf[4];
#pragma unroll
    for (int kf = 0; kf < 4; ++kf) {
      const u16* krow = &Kbase[(size_t)(k0 + kf * 16 + ll) * D];
      bf16x8 kb0 = *(const bf16x8*)&krow[lg * 8];
      bf16x8 kb1 = *(const bf16x8*)&krow[32 + lg * 8];
      f32x4 t = {0.f, 0.f, 0.f, 0.f};
      t = __builtin_amdgcn_mfma_f32_16x16x32_bf16(aQ[0], kb0, t, 0, 0, 0);
      t = __builtin_amdgcn_mfma_f32_16x16x32_bf16(aQ[1], kb1, t, 0, 0, 0);
#pragma unroll
      for (int r = 0; r < 4; ++r)
        t[r] = t[r] * SCALE +
               lam * Bbase[(size_t)(lg * 4 + r) * S + k0 + kf * 16 + ll];
      sf[kf] = t;
    }
    // ---- online softmax (rows live on 16-lane groups: xor 1,2,4,8) ----
    float cf[4];
#pragma unroll
    for (int r = 0; r < 4; ++r) {
      float pm = fmaxf(fmaxf(sf[0][r], sf[1][r]), fmaxf(sf[2][r], sf[3][r]));
      pm = fmaxf(pm, __shfl_xor(pm, 1));
      pm = fmaxf(pm, __shfl_xor(pm, 2));
      pm = fmaxf(pm, __shfl_xor(pm, 4));
      pm = fmaxf(pm, __shfl_xor(pm, 8));
      float nm = fmaxf(m_r[r], pm);
      cf[r] = __expf(m_r[r] - nm);
      m_r[r] = nm;
      float ps = 0.f;
#pragma unroll
      for (int kf = 0; kf < 4; ++kf) {
        float p = __expf(sf[kf][r] - nm);
        Pl[w][lg * 4 + r][kf * 16 + ll] = p;
        ps += p;
      }
      ps += __shfl_xor(ps, 1);
      ps += __shfl_xor(ps, 2);
      ps += __shfl_xor(ps, 4);
      ps += __shfl_xor(ps, 8);
      l_r[r] = l_r[r] * cf[r] + ps;
#pragma unroll
      for (int nf = 0; nf < 4; ++nf) accO[nf][r] *= cf[r];
    }
    // ---- P -> bf16 a-frags (row = ll, kv-slots = kvs*32 + lg*8 + j) ----
    bf16x8 aP[2];
#pragma unroll
    for (int kvs = 0; kvs < 2; ++kvs) {
      f32x4 p0 = *(const f32x4*)&Pl[w][ll][kvs * 32 + lg * 8];
      f32x4 p1 = *(const f32x4*)&Pl[w][ll][kvs * 32 + lg * 8 + 4];
      bf16x8 t;
      t[0] = (__bf16)p0[0]; t[1] = (__bf16)p0[1];
      t[2] = (__bf16)p0[2]; t[3] = (__bf16)p0[3];
      t[4] = (__bf16)p1[0]; t[5] = (__bf16)p1[1];
      t[6] = (__bf16)p1[2]; t[7] = (__bf16)p1[3];
      aP[kvs] = t;
    }
    // ---- PV: B[kv][d] = Vt[d][kv], contiguous along kv ----
#pragma unroll
    for (int nf = 0; nf < 4; ++nf) {
      const u16* vrow = &Vbase[(size_t)(nf * 16 + ll) * S + k0];
      bf16x8 v0 = *(const bf16x8*)&vrow[lg * 8];
      bf16x8 v1 = *(const bf16x8*)&vrow[32 + lg * 8];
      accO[nf] = __builtin_amdgcn_mfma_f32_16x16x32_bf16(aP[0], v0, accO[nf], 0, 0, 0);
      accO[nf] = __builtin_amdgcn_mfma_f32_16x16x32_bf16(aP[1], v1, accO[nf], 0, 0, 0);
    }
  }

  float inv[4];
#pragma unroll
  for (int r = 0; r < 4; ++r) inv[r] = 1.0f / l_r[r];
#pragma unroll
  for (int nf = 0; nf < 4; ++nf)
#pragma unroll
    for (int r = 0; r < 4; ++r)
      Ob[(size_t)(b * S + qw + lg * 4 + r) * D + h * 64 + nf * 16 + ll] =
          f2bf(accO[nf][r] * inv[r]);
}

}  // namespace

extern "C" void kernel_launch(void* const* d_in, const int* in_sizes, int n_in,
                              void* d_out, int out_size, void* d_ws, size_t ws_size,
                              hipStream_t stream)
{
  const float* query = (const float*)d_in[0];
  const float* key   = (const float*)d_in[1];
  const float* value = (const float*)d_in[2];
  const float* biasS = (const float*)d_in[3];
  const float* Wq = (const float*)d_in[4];
  const float* bq = (const float*)d_in[5];
  const float* Wk = (const float*)d_in[6];
  const float* bk = (const float*)d_in[7];
  const float* Wv = (const float*)d_in[8];
  const float* bv = (const float*)d_in[9];
  const float* Wo = (const float*)d_in[10];
  const float* bo = (const float*)d_in[11];
  const float* lam = (const float*)d_in[12];
  float* out = (float*)d_out;

  // workspace layout (48 MB total; regions reused once dead):
  char* ws = (char*)d_ws;
  const size_t MB = 1024 * 1024;
  u16* Xq  = (u16*)(ws + 0 * MB);    // 8 MB   (dead after GEMM-Q -> Vbf)
  u16* Xk  = (u16*)(ws + 8 * MB);    // 8 MB   (dead after GEMM-K -> Vt)
  u16* Xv  = (u16*)(ws + 16 * MB);   // 8 MB   (dead after GEMM-V -> Obf)
  u16* WqB = (u16*)(ws + 24 * MB);   // 2 MB
  u16* WkB = (u16*)(ws + 26 * MB);
  u16* WvB = (u16*)(ws + 28 * MB);
  u16* WoB = (u16*)(ws + 30 * MB);
  u16* Qbf = (u16*)(ws + 32 * MB);   // 8 MB
  u16* Kbf = (u16*)(ws + 40 * MB);   // 8 MB
  u16* Vbf = Xq;                     // 8 MB (aliases Xq)
  u16* Vt  = Xk;                     // 8 MB (aliases Xk)
  u16* Obf = Xv;                     // 8 MB (aliases Xv)

  // 1) fp32 -> bf16 conversions
  dim3 c3grid(GM * GN / (256 * 4) / 1, 1, 3);     // 4096 x 3
  cvt3_k<<<dim3(4096, 1, 3), 256, 0, stream>>>(query, key, value, Xq, Xk, Xv);
  cvt4_k<<<dim3(1024, 1, 4), 256, 0, stream>>>(Wq, Wk, Wv, Wo, WqB, WkB, WvB, WoB);

  // 2) projections
  dim3 ggrid(GN / 128, GM / 64);                   // (8, 64)
  gemm_bf16_k<true><<<ggrid, 256, 0, stream>>>(Xq, WqB, bq, Qbf, nullptr);
  gemm_bf16_k<true><<<ggrid, 256, 0, stream>>>(Xk, WkB, bk, Kbf, nullptr);
  gemm_bf16_k<true><<<ggrid, 256, 0, stream>>>(Xv, WvB, bv, Vbf, nullptr);

  // 3) V transpose for PV operand
  transpose_v_k<<<dim3(S / 64, B * H), 256, 0, stream>>>(Vbf, Vt);

  // 4) flash attention
  attn_mfma_k<<<dim3(S / 64, B * H), 256, 0, stream>>>(Qbf, Kbf, Vt, biasS, lam, Obf);

  // 5) output projection (fp32 out)
  gemm_bf16_k<false><<<ggrid, 256, 0, stream>>>(Obf, WoB, bo, nullptr, out);
}

// Round 4
// 364.126 us; speedup vs baseline: 4.2948x; 1.6809x over previous
//
#include <hip/hip_runtime.h>
#include <hip/hip_bf16.h>

namespace {

constexpr int B  = 2;
constexpr int S  = 2048;
constexpr int D  = 1024;
constexpr int H  = 16;
constexpr float SCALE = 0.125f;   // HD^-0.5

constexpr int GM = B * S;   // 4096
constexpr int GN = D;       // 1024
constexpr int GK = D;       // 1024

typedef __bf16 bf16x8 __attribute__((ext_vector_type(8)));
typedef float  f32x4  __attribute__((ext_vector_type(4)));
typedef unsigned short u16;
typedef u16 u16x8 __attribute__((ext_vector_type(8)));
typedef u16 u16x4 __attribute__((ext_vector_type(4)));

__device__ __forceinline__ u16 f2bf(float f) {
  union { float f; unsigned u; } v{f};
  unsigned r = v.u + 0x7fffu + ((v.u >> 16) & 1u);   // RNE
  return (u16)(r >> 16);
}

__device__ __forceinline__ f32x4 mfma16(bf16x8 a, bf16x8 b, f32x4 c) {
  return __builtin_amdgcn_mfma_f32_16x16x32_bf16(a, b, c, 0, 0, 0);
}

__device__ __forceinline__ void gload_lds16(const u16* g, u16* l) {
  __builtin_amdgcn_global_load_lds(
      (const __attribute__((address_space(1))) void*)g,
      (__attribute__((address_space(3))) void*)l, 16, 0, 0);
}

// ---------------- fp32 -> bf16 conversion (batched over blockIdx.z) --------
__global__ __launch_bounds__(256) void cvt3_k(
    const float* __restrict__ a, const float* __restrict__ b,
    const float* __restrict__ c, u16* __restrict__ da,
    u16* __restrict__ db, u16* __restrict__ dc)
{
  const float* s = (blockIdx.z == 0) ? a : (blockIdx.z == 1) ? b : c;
  u16* d = (blockIdx.z == 0) ? da : (blockIdx.z == 1) ? db : dc;
  size_t i = ((size_t)blockIdx.x * 256 + threadIdx.x) * 4;
  float4 v = *(const float4*)&s[i];
  u16x4 o = { f2bf(v.x), f2bf(v.y), f2bf(v.z), f2bf(v.w) };
  *(u16x4*)&d[i] = o;
}

__global__ __launch_bounds__(256) void cvt4_k(
    const float* __restrict__ a, const float* __restrict__ b,
    const float* __restrict__ c, const float* __restrict__ e,
    u16* __restrict__ da, u16* __restrict__ db,
    u16* __restrict__ dc, u16* __restrict__ de)
{
  const float* s = (blockIdx.z == 0) ? a : (blockIdx.z == 1) ? b
                 : (blockIdx.z == 2) ? c : e;
  u16* d = (blockIdx.z == 0) ? da : (blockIdx.z == 1) ? db
         : (blockIdx.z == 2) ? dc : de;
  size_t i = ((size_t)blockIdx.x * 256 + threadIdx.x) * 4;
  float4 v = *(const float4*)&s[i];
  u16x4 o = { f2bf(v.x), f2bf(v.y), f2bf(v.z), f2bf(v.w) };
  *(u16x4*)&d[i] = o;
}

// ---------------- bf16 MFMA GEMM, 128x128 tile, BK=64, gload_lds + swizzle -
// C[M,N] = A[M,K] @ W[N,K]^T + bias. 4 waves (2x2), wave = 64x64 out.
// LDS row-major [row][64 elems = 128B] with byte-in-row ^= (row&7)<<4
// (pre-swizzled global source; swizzled ds_read) -> conflict-free both sides.
template <bool OUTBF, int NZ>
__global__ __launch_bounds__(256) void gemm128_k(
    const u16* __restrict__ A0, const u16* __restrict__ W0, const float* __restrict__ bias0,
    const u16* __restrict__ A1, const u16* __restrict__ W1, const float* __restrict__ bias1,
    u16* __restrict__ Cb0, u16* __restrict__ Cb1, float* __restrict__ Cf)
{
  __shared__ u16 Al[2][128 * 64];   // 2 x 16 KB
  __shared__ u16 Bl[2][128 * 64];

  const int z = (NZ > 1) ? blockIdx.z : 0;
  const u16* Ap = (z == 0) ? A0 : A1;
  const u16* Wp = (z == 0) ? W0 : W1;
  const float* bias = (z == 0) ? bias0 : bias1;
  u16* Cb = (z == 0) ? Cb0 : Cb1;

  const int tid  = threadIdx.x;
  const int lane = tid & 63;
  const int w    = tid >> 6;
  const int wr = w >> 1, wc = w & 1;
  const int lg = lane >> 4, ll = lane & 15;
  const int bm = blockIdx.y * 128, bn = blockIdx.x * 128;

  auto STAGE = [&](int buf, int k0) {
#pragma unroll
    for (int i = 0; i < 4; ++i) {
      const int c   = (w * 4 + i) * 64 + lane;
      const int row = c >> 3, cs = c & 7;
      const int dofs = ((cs * 16) ^ ((row & 7) << 4)) >> 1;   // u16 units
      gload_lds16(&Ap[(size_t)(bm + row) * GK + k0 + dofs],
                  &Al[buf][(w * 4 + i) * 512]);
      gload_lds16(&Wp[(size_t)(bn + row) * GK + k0 + dofs],
                  &Bl[buf][(w * 4 + i) * 512]);
    }
  };

  f32x4 acc[4][4] = {};

  STAGE(0, 0);
  __syncthreads();                    // drains vmcnt(0): buf0 ready

  int cur = 0;
  constexpr int NT = GK / 64;         // 16
  for (int t = 0; t < NT; ++t) {
    if (t + 1 < NT) STAGE(cur ^ 1, (t + 1) * 64);
#pragma unroll
    for (int half = 0; half < 2; ++half) {
      bf16x8 af[4], bfr[4];
#pragma unroll
      for (int mi = 0; mi < 4; ++mi) {
        const int row = wr * 64 + mi * 16 + ll;
        af[mi] = *(const bf16x8*)&Al[cur][row * 64 +
                   (((half * 64 + lg * 16) ^ ((row & 7) << 4)) >> 1)];
      }
#pragma unroll
      for (int ni = 0; ni < 4; ++ni) {
        const int row = wc * 64 + ni * 16 + ll;
        bfr[ni] = *(const bf16x8*)&Bl[cur][row * 64 +
                   (((half * 64 + lg * 16) ^ ((row & 7) << 4)) >> 1)];
      }
#pragma unroll
      for (int mi = 0; mi < 4; ++mi)
#pragma unroll
        for (int ni = 0; ni < 4; ++ni)
          acc[mi][ni] = mfma16(af[mi], bfr[ni], acc[mi][ni]);
    }
    __syncthreads();                  // drains next-stage vmcnt; LDS reads done
    cur ^= 1;
  }

#pragma unroll
  for (int ni = 0; ni < 4; ++ni) {
    const int gcol = bn + wc * 64 + ni * 16 + ll;
    const float bv = bias[gcol];
#pragma unroll
    for (int mi = 0; mi < 4; ++mi) {
      const int grow = bm + wr * 64 + mi * 16 + lg * 4;
#pragma unroll
      for (int r = 0; r < 4; ++r) {
        float v = acc[mi][ni][r] + bv;
        if (OUTBF) Cb[(size_t)(grow + r) * GN + gcol] = f2bf(v);
        else       Cf[(size_t)(grow + r) * GN + gcol] = v;
      }
    }
  }
}

// ---------------- V transpose: Vbf[b,s,h*64+d] -> Vt[(b*H+h)*64+d][s] ------
__global__ __launch_bounds__(256) void transpose_v_k(
    const u16* __restrict__ Vb, u16* __restrict__ Vt)
{
  __shared__ u16 T[64][72];
  const int tid = threadIdx.x;
  const int bh = blockIdx.y, b = bh >> 4, h = bh & 15;
  const int s0 = blockIdx.x * 64;
#pragma unroll
  for (int it = 0; it < 2; ++it) {
    int idx = tid + it * 256;
    int s = idx >> 3, dc = idx & 7;
    *(uint4*)&T[s][dc * 8] =
        *(const uint4*)&Vb[(size_t)(b * S + s0 + s) * D + h * 64 + dc * 8];
  }
  __syncthreads();
#pragma unroll
  for (int it = 0; it < 2; ++it) {
    int idx = tid + it * 256;
    int d = idx >> 3, sc = idx & 7;
    u16x8 o;
#pragma unroll
    for (int jj = 0; jj < 8; ++jj) o[jj] = T[sc * 8 + jj][d];
    *(u16x8*)&Vt[((size_t)bh * 64 + d) * S + s0 + sc * 8] = o;
  }
}

// ---------------- MFMA flash attention, LDS-staged K (dbuf) ----------------
// grid (S/64, B*H), 4 waves; wave w owns 16 q-rows. K tile staged in LDS via
// global_load_lds with XOR swizzle, double-buffered (stage t+1 before compute
// of t). V fragments + next-tile bias issued early into registers. P handed
// QK^T -> PV through per-wave bf16 LDS buffer.
__global__ __launch_bounds__(256, 3) void attn_mfma2_k(
    const u16* __restrict__ Qb, const u16* __restrict__ Kb,
    const u16* __restrict__ Vt, const float* __restrict__ biasS,
    const float* __restrict__ lamp, u16* __restrict__ Ob)
{
  __shared__ u16 Kl[2][64 * 64];      // 2 x 8 KB, swizzled rows (128B)
  __shared__ u16 Pl[4][16][72];       // bf16 P, row stride 144B (16B-aligned)

  const int tid  = threadIdx.x;
  const int lane = tid & 63;
  const int w    = tid >> 6;
  const int lg = lane >> 4, ll = lane & 15;
  const int bh = blockIdx.y, b = bh >> 4, h = bh & 15;
  const int qw = blockIdx.x * 64 + w * 16;
  const float lam = lamp[0];

  bf16x8 aQ[2];
  {
    const u16* qrow = &Qb[(size_t)(b * S + qw + ll) * D + h * 64];
    aQ[0] = *(const bf16x8*)&qrow[lg * 8];
    aQ[1] = *(const bf16x8*)&qrow[32 + lg * 8];
  }

  const u16* Kbase = &Kb[(size_t)(b * S) * D + h * 64];
  const u16* Vbase = &Vt[(size_t)bh * 64 * S];
  const float* Bb  = &biasS[((size_t)b * S + qw + lg * 4) * S];

  auto STAGE_K = [&](int buf, int k0) {
#pragma unroll
    for (int i = 0; i < 2; ++i) {
      const int c   = (w * 2 + i) * 64 + lane;
      const int row = c >> 3, cs = c & 7;
      const int dofs = ((cs * 16) ^ ((row & 7) << 4)) >> 1;
      gload_lds16(&Kbase[(size_t)(k0 + row) * D + dofs],
                  &Kl[buf][(w * 2 + i) * 512]);
    }
  };

  f32x4 accO[4] = {};
  float m_r[4], l_r[4];
#pragma unroll
  for (int r = 0; r < 4; ++r) { m_r[r] = -1e30f; l_r[r] = 0.f; }

  float bc[4][4];
  STAGE_K(0, 0);
#pragma unroll
  for (int r = 0; r < 4; ++r)
#pragma unroll
    for (int kf = 0; kf < 4; ++kf)
      bc[r][kf] = Bb[(size_t)r * S + kf * 16 + ll];
  __syncthreads();                     // buf0 staged

  int cur = 0;
  constexpr int NT = S / 64;           // 32
  for (int t = 0; t < NT; ++t) {
    const int k0 = t * 64;
    if (t + 1 < NT) STAGE_K(cur ^ 1, k0 + 64);

    // V fragments for this tile, issued early (used after softmax)
    bf16x8 v0[4], v1[4];
#pragma unroll
    for (int nf = 0; nf < 4; ++nf) {
      const u16* vrow = &Vbase[(size_t)(nf * 16 + ll) * S + k0];
      v0[nf] = *(const bf16x8*)&vrow[lg * 8];
      v1[nf] = *(const bf16x8*)&vrow[32 + lg * 8];
    }
    // bias prefetch for next tile
    float bn[4][4];
    if (t + 1 < NT) {
#pragma unroll
      for (int r = 0; r < 4; ++r)
#pragma unroll
        for (int kf = 0; kf < 4; ++kf)
          bn[r][kf] = Bb[(size_t)r * S + k0 + 64 + kf * 16 + ll];
    }

    // ---- QK^T from LDS (swizzled reads) ----
    f32x4 sf[4];
#pragma unroll
    for (int kf = 0; kf < 4; ++kf) {
      const int row = kf * 16 + ll;
      const u16* kr = &Kl[cur][row * 64];
      bf16x8 kb0 = *(const bf16x8*)&kr[((lg * 16) ^ ((row & 7) << 4)) >> 1];
      bf16x8 kb1 = *(const bf16x8*)&kr[((64 + lg * 16) ^ ((row & 7) << 4)) >> 1];
      f32x4 t4 = {0.f, 0.f, 0.f, 0.f};
      t4 = mfma16(aQ[0], kb0, t4);
      t4 = mfma16(aQ[1], kb1, t4);
#pragma unroll
      for (int r = 0; r < 4; ++r)
        t4[r] = t4[r] * SCALE + lam * bc[r][kf];
      sf[kf] = t4;
    }

    // ---- online softmax (rows on 16-lane groups) ----
#pragma unroll
    for (int r = 0; r < 4; ++r) {
      float pm = fmaxf(fmaxf(sf[0][r], sf[1][r]), fmaxf(sf[2][r], sf[3][r]));
      pm = fmaxf(pm, __shfl_xor(pm, 1));
      pm = fmaxf(pm, __shfl_xor(pm, 2));
      pm = fmaxf(pm, __shfl_xor(pm, 4));
      pm = fmaxf(pm, __shfl_xor(pm, 8));
      float nm = fmaxf(m_r[r], pm);
      float cf = __expf(m_r[r] - nm);
      m_r[r] = nm;
      float ps = 0.f;
#pragma unroll
      for (int kf = 0; kf < 4; ++kf) {
        float p = __expf(sf[kf][r] - nm);
        Pl[w][lg * 4 + r][kf * 16 + ll] = f2bf(p);
        ps += p;
      }
      ps += __shfl_xor(ps, 1);
      ps += __shfl_xor(ps, 2);
      ps += __shfl_xor(ps, 4);
      ps += __shfl_xor(ps, 8);
      l_r[r] = l_r[r] * cf + ps;
#pragma unroll
      for (int nf = 0; nf < 4; ++nf) accO[nf][r] *= cf;
    }

    // ---- PV (P read back as bf16 fragments) ----
    bf16x8 aP0 = *(const bf16x8*)&Pl[w][ll][lg * 8];
    bf16x8 aP1 = *(const bf16x8*)&Pl[w][ll][32 + lg * 8];
#pragma unroll
    for (int nf = 0; nf < 4; ++nf) {
      accO[nf] = mfma16(aP0, v0[nf], accO[nf]);
      accO[nf] = mfma16(aP1, v1[nf], accO[nf]);
    }

    if (t + 1 < NT) {
#pragma unroll
      for (int r = 0; r < 4; ++r)
#pragma unroll
        for (int kf = 0; kf < 4; ++kf) bc[r][kf] = bn[r][kf];
    }
    __syncthreads();                   // next K buffer staged; Kl reads done
    cur ^= 1;
  }

  float inv[4];
#pragma unroll
  for (int r = 0; r < 4; ++r) inv[r] = 1.0f / l_r[r];
#pragma unroll
  for (int nf = 0; nf < 4; ++nf)
#pragma unroll
    for (int r = 0; r < 4; ++r)
      Ob[(size_t)(b * S + qw + lg * 4 + r) * D + h * 64 + nf * 16 + ll] =
          f2bf(accO[nf][r] * inv[r]);
}

}  // namespace

extern "C" void kernel_launch(void* const* d_in, const int* in_sizes, int n_in,
                              void* d_out, int out_size, void* d_ws, size_t ws_size,
                              hipStream_t stream)
{
  const float* query = (const float*)d_in[0];
  const float* key   = (const float*)d_in[1];
  const float* value = (const float*)d_in[2];
  const float* biasS = (const float*)d_in[3];
  const float* Wq = (const float*)d_in[4];
  const float* bq = (const float*)d_in[5];
  const float* Wk = (const float*)d_in[6];
  const float* bk = (const float*)d_in[7];
  const float* Wv = (const float*)d_in[8];
  const float* bv = (const float*)d_in[9];
  const float* Wo = (const float*)d_in[10];
  const float* bo = (const float*)d_in[11];
  const float* lam = (const float*)d_in[12];
  float* out = (float*)d_out;

  // workspace layout (48 MB total; regions reused once dead):
  char* ws = (char*)d_ws;
  const size_t MB = 1024 * 1024;
  u16* Xq  = (u16*)(ws + 0 * MB);    // 8 MB   (dead after GEMM-Q -> Vbf)
  u16* Xk  = (u16*)(ws + 8 * MB);    // 8 MB   (dead after GEMM-K -> Vt)
  u16* Xv  = (u16*)(ws + 16 * MB);   // 8 MB   (dead after GEMM-V -> Obf)
  u16* WqB = (u16*)(ws + 24 * MB);   // 2 MB
  u16* WkB = (u16*)(ws + 26 * MB);
  u16* WvB = (u16*)(ws + 28 * MB);
  u16* WoB = (u16*)(ws + 30 * MB);
  u16* Qbf = (u16*)(ws + 32 * MB);   // 8 MB
  u16* Kbf = (u16*)(ws + 40 * MB);   // 8 MB
  u16* Vbf = Xq;                     // aliases Xq (written after Q-GEMM done)
  u16* Vt  = Xk;                     // aliases Xk
  u16* Obf = Xv;                     // aliases Xv

  // 1) fp32 -> bf16 conversions
  cvt3_k<<<dim3(4096, 1, 3), 256, 0, stream>>>(query, key, value, Xq, Xk, Xv);
  cvt4_k<<<dim3(1024, 1, 4), 256, 0, stream>>>(Wq, Wk, Wv, Wo, WqB, WkB, WvB, WoB);

  // 2) projections: Q,K fused (z=2); V separate (its output aliases Xq)
  dim3 pgrid(GN / 128, GM / 128, 2);               // (8, 32, 2)
  gemm128_k<true, 2><<<pgrid, 256, 0, stream>>>(
      Xq, WqB, bq, Xk, WkB, bk, Qbf, Kbf, nullptr);
  dim3 vgrid(GN / 128, GM / 128, 1);
  gemm128_k<true, 1><<<vgrid, 256, 0, stream>>>(
      Xv, WvB, bv, nullptr, nullptr, nullptr, Vbf, nullptr, nullptr);

  // 3) V transpose for PV operand
  transpose_v_k<<<dim3(S / 64, B * H), 256, 0, stream>>>(Vbf, Vt);

  // 4) flash attention
  attn_mfma2_k<<<dim3(S / 64, B * H), 256, 0, stream>>>(Qbf, Kbf, Vt, biasS, lam, Obf);

  // 5) output projection (fp32 out)
  gemm128_k<false, 1><<<vgrid, 256, 0, stream>>>(
      Obf, WoB, bo, nullptr, nullptr, nullptr, nullptr, nullptr, out);
}